// Round 3
// baseline (211.532 us; speedup 1.0000x reference)
//
#include <hip/hip_runtime.h>

// TrimZeros: reference masks out columns strictly beyond the last nonzero
// column. Those columns are all-zero in the input by definition, so the
// reference output is bitwise-equal (up to ±0.0, which absmax treats as 0)
// to the input for ANY input. The op is an identity copy: 512 MiB read +
// 512 MiB write = 1.074 GB HBM traffic, memory-bound.
//
// R1: hipMemcpyAsync blit path = 5.12 TB/s; harness fill kernel sustains
// 6.4-6.7 TB/s on this chip. Grid-stride 16 B/lane copy with non-temporal
// hints (stream >> 256 MiB L3, zero reuse) targets the ~6.3 TB/s kernel
// ceiling -> ~170 us.
//
// R2 fix: __builtin_nontemporal_* requires a NATIVE vector type, not HIP's
// HIP_vector_type<float,4> class -> use ext_vector_type(4).

typedef float f4 __attribute__((ext_vector_type(4)));

__global__ __launch_bounds__(256) void trimzeros_copy_f4(
    const f4* __restrict__ src, f4* __restrict__ dst, size_t n4) {
    size_t i = (size_t)blockIdx.x * blockDim.x + threadIdx.x;
    const size_t stride = (size_t)gridDim.x * blockDim.x;
    for (; i < n4; i += stride) {
        f4 v = __builtin_nontemporal_load(&src[i]);
        __builtin_nontemporal_store(v, &dst[i]);
    }
}

extern "C" void kernel_launch(void* const* d_in, const int* in_sizes, int n_in,
                              void* d_out, int out_size, void* d_ws, size_t ws_size,
                              hipStream_t stream) {
    const f4* x = (const f4*)d_in[0];
    f4* out = (f4*)d_out;
    // out_size = F*L = 1024*131072 = 134,217,728 floats; divisible by 4.
    const size_t n4 = (size_t)out_size / 4;
    const int block = 256;
    const int grid = 2048;  // grid-stride: 64 float4 iterations per thread
    trimzeros_copy_f4<<<grid, block, 0, stream>>>(x, out, n4);
}